// Round 1
// baseline (926.235 us; speedup 1.0000x reference)
//
#include <hip/hip_runtime.h>

#define NNODES 40960
#define NEDGES 81920
#define NG     1024
#define NPG    40
#define DIN    64
#define DOUT   32
#define NCOMBO 512

// ---------- atom encoder: x[n,d] = sum_c atom_emb[c, nf[n,c], d] ----------
__global__ void k_atom(const int* __restrict__ nf, const float* __restrict__ emb,
                       float* __restrict__ x) {
    int gid = blockIdx.x * blockDim.x + threadIdx.x;   // NNODES*64
    int n = gid >> 6, d = gid & 63;
    const int* nfr = nf + n * 9;
    float acc = 0.f;
#pragma unroll
    for (int c = 0; c < 9; ++c) {
        int idx = nfr[c];                                // broadcast across lanes
        acc += emb[((c << 7) + idx) * 64 + d];
    }
    x[gid] = acc;
}

// ---------- out_init[n,o] = bias[o] + sum_d x[n,d]*root[d,o] ----------
__global__ void k_rootinit(const float* __restrict__ x, const float* __restrict__ root,
                           const float* __restrict__ bias, float* __restrict__ out) {
    int gid = blockIdx.x * blockDim.x + threadIdx.x;   // NNODES*32
    int n = gid >> 5, o = gid & 31;
    const float* xr = x + n * 64;
    float acc = bias[o];
#pragma unroll
    for (int d = 0; d < 64; ++d) acc += xr[d] * root[d * 32 + o];
    out[gid] = acc;
}

// ---------- dedup: combo id per edge ----------
__global__ void k_cid(const int* __restrict__ ef, int* __restrict__ cid) {
    int e = blockIdx.x * blockDim.x + threadIdx.x;
    if (e < NEDGES)
        cid[e] = (ef[e * 3] << 6) | (ef[e * 3 + 1] << 3) | ef[e * 3 + 2];
}

// ---------- etab[c,j] = bond_emb[0,f0,j]+bond_emb[1,f1,j]+bond_emb[2,f2,j] ----------
__global__ void k_etab(const float* __restrict__ bemb, float* __restrict__ etab) {
    int gid = blockIdx.x * blockDim.x + threadIdx.x;   // 512*16
    int c = gid >> 4, j = gid & 15;
    int f0 = c >> 6, f1 = (c >> 3) & 7, f2 = c & 7;
    etab[gid] = bemb[(0 * 8 + f0) * 16 + j] + bemb[(1 * 8 + f1) * 16 + j] +
                bemb[(2 * 8 + f2) * 16 + j];
}

// ---------- naive GEMM: C = opt_relu(A[M,K] @ B[K,N] + bias) ----------
__global__ void k_gemm_naive(const float* __restrict__ A, const float* __restrict__ B,
                             const float* __restrict__ bias, float* __restrict__ C,
                             int M, int N, int K, int relu) {
    int gid = blockIdx.x * blockDim.x + threadIdx.x;
    if (gid >= M * N) return;
    int m = gid / N, n = gid - m * N;
    const float* a = A + m * K;
    float acc = bias ? bias[n] : 0.f;
    for (int k = 0; k < K; ++k) acc += a[k] * B[k * N + n];
    if (relu) acc = fmaxf(acc, 0.f);
    C[gid] = acc;
}

// ---------- row-tiled GEMM: block=256 cols, TM rows per block, K%64==0, N%256==0 ----------
template <int TM>
__global__ void k_gemm_rowtile(const float* __restrict__ A, const float* __restrict__ B,
                               const float* __restrict__ bias, float* __restrict__ C,
                               int M, int N, int K, int relu) {
    __shared__ float As[TM][64];
    int col = blockIdx.x * 256 + threadIdx.x;
    int row0 = blockIdx.y * TM;
    float acc[TM];
#pragma unroll
    for (int r = 0; r < TM; ++r) acc[r] = 0.f;
    for (int k0 = 0; k0 < K; k0 += 64) {
#pragma unroll
        for (int i = 0; i < (TM * 64) / 256; ++i) {
            int idx = i * 256 + threadIdx.x;
            int r = idx >> 6, k = idx & 63;
            As[r][k] = A[(row0 + r) * K + k0 + k];
        }
        __syncthreads();
#pragma unroll 16
        for (int k = 0; k < 64; ++k) {
            float b = B[(k0 + k) * N + col];
#pragma unroll
            for (int r = 0; r < TM; ++r) acc[r] += As[r][k] * b;
        }
        __syncthreads();
    }
#pragma unroll
    for (int r = 0; r < TM; ++r) {
        float v = acc[r] + (bias ? bias[col] : 0.f);
        if (relu) v = fmaxf(v, 0.f);
        C[(row0 + r) * N + col] = v;
    }
}

// ---------- NNConv message + scatter: out[dst,o] += sum_d x[src,d]*wtab[cid,d*32+o] ----------
__global__ void k_msg(const float* __restrict__ x, const float* __restrict__ wtab,
                      const int* __restrict__ cid, const int* __restrict__ src,
                      const int* __restrict__ dst, float* __restrict__ out) {
    int gid = blockIdx.x * blockDim.x + threadIdx.x;   // NEDGES*32
    int e = gid >> 5, o = gid & 31;
    int s = src[e], d = dst[e], c = cid[e];
    const float* xr = x + s * 64;
    const float* w = wtab + c * 2048 + o;
    float acc = 0.f;
#pragma unroll
    for (int k = 0; k < 64; ++k) acc += xr[k] * w[k * 32];
    atomicAdd(&out[d * 32 + o], acc);
}

extern "C" void kernel_launch(void* const* d_in, const int* in_sizes, int n_in,
                              void* d_out, int out_size, void* d_ws, size_t ws_size,
                              hipStream_t stream) {
    const int*   nf      = (const int*)d_in[0];
    const int*   ef      = (const int*)d_in[1];
    const int*   eidx    = (const int*)d_in[2];
    const float* atom_emb= (const float*)d_in[4];
    const float* bond_emb= (const float*)d_in[5];
    const float* gW1     = (const float*)d_in[6];
    const float* gW2     = (const float*)d_in[7];
    const float* gW3     = (const float*)d_in[8];
    const float* root    = (const float*)d_in[9];
    const float* cbias   = (const float*)d_in[10];
    const float* mW1     = (const float*)d_in[11];
    const float* mb1     = (const float*)d_in[12];
    const float* mW2     = (const float*)d_in[13];
    const float* mb2     = (const float*)d_in[14];
    const float* mW3     = (const float*)d_in[15];
    const float* mb3     = (const float*)d_in[16];
    const float* mW4     = (const float*)d_in[17];
    const float* mb4     = (const float*)d_in[18];
    const float* mW5     = (const float*)d_in[19];
    const float* mb5     = (const float*)d_in[20];

    const int* src = eidx;
    const int* dst = eidx + NEDGES;

    float* ws = (float*)d_ws;
    float* x    = ws;                       // 40960*64   = 2621440
    float* out  = x + 2621440;              // 40960*32   = 1310720
    float* etab = out + 1310720;            // 512*16     = 8192
    float* h1   = etab + 8192;              // 512*1024   = 524288
    float* h2   = h1 + 524288;              // 512*256    = 131072
    float* wtab = h2 + 131072;              // 512*2048   = 1048576
    float* f1   = wtab + 1048576;           // 1024*256   = 262144
    float* f2   = f1 + 262144;              // 1024*128   = 131072
    float* f3   = f2 + 131072;              // 1024*32    = 32768
    float* f4   = f3 + 32768;               // 1024*8     = 8192
    int*   cid  = (int*)(f4 + 8192);        // 81920 ints

    // 1. atom encoder
    k_atom<<<NNODES * 64 / 256, 256, 0, stream>>>(nf, atom_emb, x);
    // 2. out = x@root + bias (agg initializer)
    k_rootinit<<<NNODES * 32 / 256, 256, 0, stream>>>(x, root, cbias, out);
    // 3. edge combo ids + dedup'd edge embeddings
    k_cid<<<(NEDGES + 255) / 256, 256, 0, stream>>>(ef, cid);
    k_etab<<<NCOMBO * 16 / 256, 256, 0, stream>>>(bond_emb, etab);
    // 4. edge MLP on 512 unique combos
    k_gemm_naive<<<NCOMBO * 1024 / 256, 256, 0, stream>>>(etab, gW1, nullptr, h1,
                                                          NCOMBO, 1024, 16, 1);
    k_gemm_rowtile<8><<<dim3(1, NCOMBO / 8), 256, 0, stream>>>(h1, gW2, nullptr, h2,
                                                               NCOMBO, 256, 1024, 1);
    k_gemm_rowtile<8><<<dim3(8, NCOMBO / 8), 256, 0, stream>>>(h2, gW3, nullptr, wtab,
                                                               NCOMBO, 2048, 256, 0);
    // 5. per-edge message + scatter-add
    k_msg<<<NEDGES * 32 / 256, 256, 0, stream>>>(x, wtab, cid, src, dst, out);
    // 6. readout MLP (padding slots 40..50 are zero -> only 1280 of 1632 K rows)
    k_gemm_rowtile<8><<<dim3(1, NG / 8), 256, 0, stream>>>(out, mW1, mb1, f1,
                                                           NG, 256, 1280, 1);
    k_gemm_naive<<<NG * 128 / 256, 256, 0, stream>>>(f1, mW2, mb2, f2, NG, 128, 256, 1);
    k_gemm_naive<<<NG * 32 / 256, 256, 0, stream>>>(f2, mW3, mb3, f3, NG, 32, 128, 1);
    k_gemm_naive<<<NG * 8 / 256, 256, 0, stream>>>(f3, mW4, mb4, f4, NG, 8, 32, 1);
    k_gemm_naive<<<NG / 256, 256, 0, stream>>>(f4, mW5, mb5, (float*)d_out, NG, 1, 8, 0);
}

// Round 2
// 235.702 us; speedup vs baseline: 3.9297x; 3.9297x over previous
//
#include <hip/hip_runtime.h>

#define NNODES 40960
#define NEDGES 81920
#define NG     1024
#define NCOMBO 512

// ---------- atom encoder: x[n,d] = sum_c atom_emb[c, nf[n,c], d] ----------
__global__ void k_atom(const int* __restrict__ nf, const float* __restrict__ emb,
                       float* __restrict__ x) {
    int gid = blockIdx.x * blockDim.x + threadIdx.x;   // NNODES*64
    int n = gid >> 6, d = gid & 63;
    const int* nfr = nf + n * 9;
    float acc = 0.f;
#pragma unroll
    for (int c = 0; c < 9; ++c) {
        int idx = nfr[c];
        acc += emb[((c << 7) + idx) * 64 + d];
    }
    x[gid] = acc;
}

// ---------- out_init[n,o] = bias[o] + sum_d x[n,d]*root[d,o] ----------
__global__ void k_rootinit(const float* __restrict__ x, const float* __restrict__ root,
                           const float* __restrict__ bias, float* __restrict__ out) {
    int gid = blockIdx.x * blockDim.x + threadIdx.x;   // NNODES*32
    int n = gid >> 5, o = gid & 31;
    const float* xr = x + n * 64;
    float acc = bias[o];
#pragma unroll
    for (int d = 0; d < 64; ++d) acc += xr[d] * root[d * 32 + o];
    out[gid] = acc;
}

// ---------- dedup: combo id per edge ----------
__global__ void k_cid(const int* __restrict__ ef, int* __restrict__ cid) {
    int e = blockIdx.x * blockDim.x + threadIdx.x;
    if (e < NEDGES)
        cid[e] = (ef[e * 3] << 6) | (ef[e * 3 + 1] << 3) | ef[e * 3 + 2];
}

// ---------- etab[c,j] = sum of 3 bond embeddings ----------
__global__ void k_etab(const float* __restrict__ bemb, float* __restrict__ etab) {
    int gid = blockIdx.x * blockDim.x + threadIdx.x;   // 512*16
    int c = gid >> 4, j = gid & 15;
    int f0 = c >> 6, f1 = (c >> 3) & 7, f2 = c & 7;
    etab[gid] = bemb[(0 * 8 + f0) * 16 + j] + bemb[(1 * 8 + f1) * 16 + j] +
                bemb[(2 * 8 + f2) * 16 + j];
}

// ---------- naive GEMM (small K only): C = relu?(A@B + bias) ----------
__global__ void k_gemm_naive(const float* __restrict__ A, const float* __restrict__ B,
                             const float* __restrict__ bias, float* __restrict__ C,
                             int M, int N, int K, int relu) {
    int gid = blockIdx.x * blockDim.x + threadIdx.x;
    if (gid >= M * N) return;
    int m = gid / N, n = gid - m * N;
    const float* a = A + m * K;
    float acc = bias ? bias[n] : 0.f;
    for (int k = 0; k < K; ++k) acc += a[k] * B[k * N + n];
    if (relu) acc = fmaxf(acc, 0.f);
    C[gid] = acc;
}

// ---------- tiled GEMM, 64x64 block tile, 4x4 micro tile, split-K over z ----------
// If gridDim.z == 1: write C with bias/relu. Else: write raw partial to Cp + z*M*N.
template <int BM, int BN, int BK, int TM, int TN>
__global__ __launch_bounds__(256)
void k_gemm_tiled(const float* __restrict__ A, const float* __restrict__ B,
                  const float* __restrict__ bias, float* __restrict__ C,
                  float* __restrict__ Cp, int M, int N, int K, int KS, int relu) {
    constexpr int TX = BN / TN;                 // 16
    constexpr int TY = BM / TM;                 // 16
    static_assert(TX * TY == 256, "block must be 256 threads");
    __shared__ float As[BK][BM + 4];            // transposed A tile
    __shared__ float Bs[BK][BN + 4];
    const int tx = threadIdx.x % TX, ty = threadIdx.x / TX;
    const int row0 = blockIdx.y * BM, col0 = blockIdx.x * BN;
    const int z = blockIdx.z;
    const int k_begin = z * KS, k_end = k_begin + KS;

    // one float4 per thread per tile
    const int am = threadIdx.x >> 2;            // 0..63
    const int ak = (threadIdx.x & 3) << 2;      // 0,4,8,12
    const int bk = threadIdx.x >> 4;            // 0..15
    const int bn = (threadIdx.x & 15) << 2;     // 0..60

    float acc[TM][TN] = {};
    for (int k0 = k_begin; k0 < k_end; k0 += BK) {
        float4 av = *reinterpret_cast<const float4*>(&A[(row0 + am) * K + k0 + ak]);
        float4 bv = *reinterpret_cast<const float4*>(&B[(k0 + bk) * N + col0 + bn]);
        As[ak + 0][am] = av.x;
        As[ak + 1][am] = av.y;
        As[ak + 2][am] = av.z;
        As[ak + 3][am] = av.w;
        *reinterpret_cast<float4*>(&Bs[bk][bn]) = bv;
        __syncthreads();
#pragma unroll
        for (int k = 0; k < BK; ++k) {
            float a[TM], b[TN];
            *reinterpret_cast<float4*>(a) =
                *reinterpret_cast<const float4*>(&As[k][ty * TM]);
            *reinterpret_cast<float4*>(b) =
                *reinterpret_cast<const float4*>(&Bs[k][tx * TN]);
#pragma unroll
            for (int i = 0; i < TM; ++i)
#pragma unroll
                for (int j = 0; j < TN; ++j) acc[i][j] += a[i] * b[j];
        }
        __syncthreads();
    }

    const int MN = M * N;
    if (gridDim.z == 1) {
#pragma unroll
        for (int i = 0; i < TM; ++i) {
            int r = row0 + ty * TM + i;
            float4 v;
            v.x = acc[i][0]; v.y = acc[i][1]; v.z = acc[i][2]; v.w = acc[i][3];
            int c = col0 + tx * TN;
            if (bias) { v.x += bias[c]; v.y += bias[c+1]; v.z += bias[c+2]; v.w += bias[c+3]; }
            if (relu) { v.x = fmaxf(v.x,0.f); v.y = fmaxf(v.y,0.f);
                        v.z = fmaxf(v.z,0.f); v.w = fmaxf(v.w,0.f); }
            *reinterpret_cast<float4*>(&C[r * N + c]) = v;
        }
    } else {
        float* dstp = Cp + z * MN;
#pragma unroll
        for (int i = 0; i < TM; ++i) {
            int r = row0 + ty * TM + i;
            float4 v;
            v.x = acc[i][0]; v.y = acc[i][1]; v.z = acc[i][2]; v.w = acc[i][3];
            *reinterpret_cast<float4*>(&dstp[r * N + col0 + tx * TN]) = v;
        }
    }
}

// ---------- split-K reduce: C = relu?(sum_z Cp[z] + bias) ----------
__global__ void k_reduceK(const float* __restrict__ Cp, const float* __restrict__ bias,
                          float* __restrict__ C, int MN, int N, int nz, int relu) {
    int i4 = (blockIdx.x * 256 + threadIdx.x) * 4;
    if (i4 >= MN) return;
    float4 acc = *reinterpret_cast<const float4*>(&Cp[i4]);
    for (int z = 1; z < nz; ++z) {
        float4 t = *reinterpret_cast<const float4*>(&Cp[z * MN + i4]);
        acc.x += t.x; acc.y += t.y; acc.z += t.z; acc.w += t.w;
    }
    if (bias) {
        int c = i4 % N;
        acc.x += bias[c]; acc.y += bias[c + 1]; acc.z += bias[c + 2]; acc.w += bias[c + 3];
    }
    if (relu) {
        acc.x = fmaxf(acc.x, 0.f); acc.y = fmaxf(acc.y, 0.f);
        acc.z = fmaxf(acc.z, 0.f); acc.w = fmaxf(acc.w, 0.f);
    }
    *reinterpret_cast<float4*>(&C[i4]) = acc;
}

// ---------- NNConv message + scatter ----------
__global__ void k_msg(const float* __restrict__ x, const float* __restrict__ wtab,
                      const int* __restrict__ cid, const int* __restrict__ src,
                      const int* __restrict__ dst, float* __restrict__ out) {
    int gid = blockIdx.x * blockDim.x + threadIdx.x;   // NEDGES*32
    int e = gid >> 5, o = gid & 31;
    int s = src[e], d = dst[e], c = cid[e];
    const float* xr = x + s * 64;
    const float* w = wtab + c * 2048 + o;
    float acc = 0.f;
#pragma unroll
    for (int k = 0; k < 64; ++k) acc += xr[k] * w[k * 32];
    atomicAdd(&out[d * 32 + o], acc);
}

// ---------- fused readout tail: f2[1024,128] -> f3 -> f4 -> out[1024] ----------
__global__ __launch_bounds__(256) void k_tail(
    const float* __restrict__ f2,
    const float* __restrict__ mW3, const float* __restrict__ mb3,
    const float* __restrict__ mW4, const float* __restrict__ mb4,
    const float* __restrict__ mW5, const float* __restrict__ mb5,
    float* __restrict__ outv) {
    __shared__ float s2[4][128];
    __shared__ float s3[4][32];
    __shared__ float s4[4][8];
    const int w = threadIdx.x >> 6, lane = threadIdx.x & 63;
    const int g = blockIdx.x * 4 + w;
    s2[w][lane] = f2[g * 128 + lane];
    s2[w][64 + lane] = f2[g * 128 + 64 + lane];
    __syncthreads();
    if (lane < 32) {
        float acc = mb3[lane];
#pragma unroll 8
        for (int k = 0; k < 128; ++k) acc += s2[w][k] * mW3[k * 32 + lane];
        s3[w][lane] = fmaxf(acc, 0.f);
    }
    __syncthreads();
    if (lane < 8) {
        float acc = mb4[lane];
#pragma unroll
        for (int k = 0; k < 32; ++k) acc += s3[w][k] * mW4[k * 8 + lane];
        s4[w][lane] = fmaxf(acc, 0.f);
    }
    __syncthreads();
    if (lane == 0) {
        float acc = mb5[0];
#pragma unroll
        for (int k = 0; k < 8; ++k) acc += s4[w][k] * mW5[k];
        outv[g] = acc;
    }
}

extern "C" void kernel_launch(void* const* d_in, const int* in_sizes, int n_in,
                              void* d_out, int out_size, void* d_ws, size_t ws_size,
                              hipStream_t stream) {
    const int*   nf      = (const int*)d_in[0];
    const int*   ef      = (const int*)d_in[1];
    const int*   eidx    = (const int*)d_in[2];
    const float* atom_emb= (const float*)d_in[4];
    const float* bond_emb= (const float*)d_in[5];
    const float* gW1     = (const float*)d_in[6];
    const float* gW2     = (const float*)d_in[7];
    const float* gW3     = (const float*)d_in[8];
    const float* root    = (const float*)d_in[9];
    const float* cbias   = (const float*)d_in[10];
    const float* mW1     = (const float*)d_in[11];
    const float* mb1     = (const float*)d_in[12];
    const float* mW2     = (const float*)d_in[13];
    const float* mb2     = (const float*)d_in[14];
    const float* mW3     = (const float*)d_in[15];
    const float* mb3     = (const float*)d_in[16];
    const float* mW4     = (const float*)d_in[17];
    const float* mb4     = (const float*)d_in[18];
    const float* mW5     = (const float*)d_in[19];
    const float* mb5     = (const float*)d_in[20];

    const int* src = eidx;
    const int* dst = eidx + NEDGES;

    float* ws = (float*)d_ws;
    float* x    = ws;                       // 40960*64   = 2621440
    float* out  = x + 2621440;              // 40960*32   = 1310720
    float* etab = out + 1310720;            // 512*16     = 8192
    float* h1   = etab + 8192;              // 512*1024   = 524288
    float* h2   = h1 + 524288;              // 512*256    = 131072
    float* wtab = h2 + 131072;              // 512*2048   = 1048576
    float* f1   = wtab + 1048576;           // 1024*256   = 262144
    float* f2   = f1 + 262144;              // 1024*128   = 131072
    float* part = f2 + 131072;              // 2097152 (8 MB split-K partials, reused)
    int*   cid  = (int*)(part + 2097152);   // 81920 ints

    // 1. atom encoder + root transform (agg initializer)
    k_atom<<<NNODES * 64 / 256, 256, 0, stream>>>(nf, atom_emb, x);
    k_rootinit<<<NNODES * 32 / 256, 256, 0, stream>>>(x, root, cbias, out);
    // 2. edge combo ids + dedup'd edge embeddings
    k_cid<<<(NEDGES + 255) / 256, 256, 0, stream>>>(ef, cid);
    k_etab<<<NCOMBO * 16 / 256, 256, 0, stream>>>(bond_emb, etab);
    // 3. edge MLP on 512 unique combos
    k_gemm_naive<<<NCOMBO * 1024 / 256, 256, 0, stream>>>(etab, gW1, nullptr, h1,
                                                          NCOMBO, 1024, 16, 1);
    // h2 = relu(h1 @ gW2): 512x256, K=1024, split 16x64
    k_gemm_tiled<64, 64, 16, 4, 4><<<dim3(4, 8, 16), 256, 0, stream>>>(
        h1, gW2, nullptr, nullptr, part, NCOMBO, 256, 1024, 64, 0);
    k_reduceK<<<131072 / 1024, 256, 0, stream>>>(part, nullptr, h2, 131072, 256, 16, 1);
    // wtab = h2 @ gW3: 512x2048, K=256, split 2x128
    k_gemm_tiled<64, 64, 16, 4, 4><<<dim3(32, 8, 2), 256, 0, stream>>>(
        h2, gW3, nullptr, nullptr, part, NCOMBO, 2048, 256, 128, 0);
    k_reduceK<<<1048576 / 1024, 256, 0, stream>>>(part, nullptr, wtab, 1048576, 2048, 2, 0);
    // 4. per-edge message + scatter-add
    k_msg<<<NEDGES * 32 / 256, 256, 0, stream>>>(x, wtab, cid, src, dst, out);
    // 5. readout: f1 = relu(dense @ mW1 + mb1), dense == out viewed [1024,1280]
    k_gemm_tiled<64, 64, 16, 4, 4><<<dim3(4, 16, 8), 256, 0, stream>>>(
        out, mW1, nullptr, nullptr, part, NG, 256, 1280, 160, 0);
    k_reduceK<<<262144 / 1024, 256, 0, stream>>>(part, mb1, f1, 262144, 256, 8, 1);
    // f2 = relu(f1 @ mW2 + mb2): 1024x128, K=256, split 4x64
    k_gemm_tiled<64, 64, 16, 4, 4><<<dim3(2, 16, 4), 256, 0, stream>>>(
        f1, mW2, nullptr, nullptr, part, NG, 128, 256, 64, 0);
    k_reduceK<<<131072 / 1024, 256, 0, stream>>>(part, mb2, f2, 131072, 128, 4, 1);
    // 6. fused tail: f3, f4, final
    k_tail<<<NG / 4, 256, 0, stream>>>(f2, mW3, mb3, mW4, mb4, mW5, mb5, (float*)d_out);
}